// Round 1
// baseline (118.322 us; speedup 1.0000x reference)
//
#include <hip/hip_runtime.h>

// RelativePositionAttention collapses algebraically:
//   softmax over w of (Q[t] - K[w]) is independent of Q (shift invariance),
//   and einsum('btdh,btwdh->btdh', Vh, A) = Vh * sum_w A = Vh * 1 = Vh.
// So: result = values @ M^T, where
//   M[e',e] = sum_{d,h} Wp[e', d*H+h] * Wv[h*E+d, e]   (256x256)
// LayerNorm / Wq / Wk are dead code.

constexpr int E  = 256;
constexpr int H  = 4;
constexpr int EH = E * H;   // 1024
constexpr int BT = 512;     // B*T

// Kernel 1: build M transposed: MT[j*E + i] = M[i][j]
//   M[i][j] = sum_{h,d} Wp[i*EH + d*H + h] * Wv[(h*E + d)*E + j]
// 64 blocks x 256 threads; each block computes 4 rows i (Wp rows staged in
// LDS, broadcast across lanes); Wv loads coalesced across j=threadIdx.x.
__global__ __launch_bounds__(256) void build_m_kernel(
    const float* __restrict__ Wv, const float* __restrict__ Wp,
    float* __restrict__ MT)
{
    const int j  = threadIdx.x;
    const int i0 = blockIdx.x * 4;

    __shared__ float sWp[4 * EH];   // 16 KB
    for (int t = threadIdx.x; t < 4 * EH; t += 256)
        sWp[t] = Wp[i0 * EH + t];
    __syncthreads();

    float a0 = 0.f, a1 = 0.f, a2 = 0.f, a3 = 0.f;
    #pragma unroll
    for (int h = 0; h < H; ++h) {
        const float* wvcol = Wv + (h * E) * E + j;   // row h*E+d, col j
        for (int d = 0; d < E; ++d) {
            const float wv = wvcol[d * E];           // coalesced across j
            const int   k  = d * H + h;
            a0 += sWp[0 * EH + k] * wv;              // LDS broadcast
            a1 += sWp[1 * EH + k] * wv;
            a2 += sWp[2 * EH + k] * wv;
            a3 += sWp[3 * EH + k] * wv;
        }
    }
    // transposed store (uncoalesced, but only 256 KB total — negligible)
    MT[j * E + i0 + 0] = a0;
    MT[j * E + i0 + 1] = a1;
    MT[j * E + i0 + 2] = a2;
    MT[j * E + i0 + 3] = a3;
}

// Kernel 2: out[r, e] = sum_j values[r, j] * MT[j*E + e]
// 128 blocks x 256 threads; 4 rows r per block (values rows in LDS,
// broadcast reads); MT row loads and out stores coalesced across e.
__global__ __launch_bounds__(256) void apply_kernel(
    const float* __restrict__ values, const float* __restrict__ MT,
    float* __restrict__ out)
{
    const int e  = threadIdx.x;
    const int r0 = blockIdx.x * 4;

    __shared__ float sv[4 * E];     // 4 KB
    for (int t = threadIdx.x; t < 4 * E; t += 256)
        sv[t] = values[r0 * E + t];
    __syncthreads();

    float a0 = 0.f, a1 = 0.f, a2 = 0.f, a3 = 0.f;
    for (int j = 0; j < E; ++j) {
        const float m = MT[j * E + e];               // coalesced across e
        a0 += sv[0 * E + j] * m;                     // LDS broadcast
        a1 += sv[1 * E + j] * m;
        a2 += sv[2 * E + j] * m;
        a3 += sv[3 * E + j] * m;
    }
    out[(r0 + 0) * E + e] = a0;
    out[(r0 + 1) * E + e] = a1;
    out[(r0 + 2) * E + e] = a2;
    out[(r0 + 3) * E + e] = a3;
}

extern "C" void kernel_launch(void* const* d_in, const int* in_sizes, int n_in,
                              void* d_out, int out_size, void* d_ws, size_t ws_size,
                              hipStream_t stream) {
    // setup_inputs order:
    // 0: position_embeddings (unused — LN/Q/K cancel)
    // 1: values
    // 2: ln_w (unused)  3: ln_b (unused)
    // 4: Wq (unused)    5: Wk (unused)
    // 6: Wv [EH, E]     7: Wp [E, EH]
    const float* values = (const float*)d_in[1];
    const float* Wv     = (const float*)d_in[6];
    const float* Wp     = (const float*)d_in[7];
    float*       out    = (float*)d_out;
    float*       MT     = (float*)d_ws;   // E*E floats = 256 KB scratch

    build_m_kernel<<<E / 4, 256, 0, stream>>>(Wv, Wp, MT);
    apply_kernel<<<BT / 4, 256, 0, stream>>>(values, MT, out);
}

// Round 2
// 102.367 us; speedup vs baseline: 1.1559x; 1.1559x over previous
//
#include <hip/hip_runtime.h>

// RelativePositionAttention collapses algebraically:
//   softmax over w of (Q[t] - K[w]) is independent of Q (shift invariance),
//   and einsum('btdh,btwdh->btdh', Vh, A) = Vh * sum_w A = Vh.
// So: result = values @ M^T, with M[i][j] = sum_{h,d} Wp[i*EH + d*H+h] * Wv[(h*E+d)*E + j].
// LayerNorm / Wq / Wk / position_embeddings are dead code.
//
// R2: fix latency-bound R1 (occupancy 2.6%, VALUBusy 3.5%).
//  - build: grid(64,4) x 1024thr, outer k-split via atomicAdd (MT zeroed by
//    hipMemsetAsync), wave = one M row over a 256-k slice. 4 waves/SIMD.
//  - apply: 128 blocks x 1024thr, wave = one output row, coalesced MT loads.

constexpr int E  = 256;
constexpr int H  = 4;
constexpr int EH = E * H;   // 1024
constexpr int BT = 512;     // B*T

// MT[j*E + i] += sum over this block's k-slice of Wp[i][k'] * Wv[perm(k')][j]
// grid (64 i-groups, 4 k-chunks), block 1024: tid = w*256 + j, row i = i0+w.
__global__ __launch_bounds__(1024) void build_m_kernel(
    const float* __restrict__ Wv, const float* __restrict__ Wp,
    float* __restrict__ MT)
{
    const int tid = threadIdx.x;
    const int j   = tid & 255;
    const int w   = tid >> 8;            // 0..3 -> which M row
    const int i0  = blockIdx.x * 4;
    const int d0  = blockIdx.y * 64;     // this block's d-range [d0, d0+64)

    // Wp row segment: k' = (d0+dd)*H + h spans [blockIdx.y*256, +256) contiguously
    __shared__ float sWp[4][256];
    sWp[w][j] = Wp[(i0 + w) * EH + blockIdx.y * 256 + j];
    __syncthreads();

    float acc = 0.f;
    #pragma unroll
    for (int h = 0; h < H; ++h) {
        const float* __restrict__ wvp = Wv + (h * E + d0) * E + j; // coalesced across j
        #pragma unroll 8
        for (int dd = 0; dd < 64; ++dd) {
            acc += sWp[w][dd * 4 + h] * wvp[dd * E];  // LDS broadcast * coalesced load
        }
    }
    atomicAdd(&MT[j * E + i0 + w], acc);  // transposed store; k-chunks accumulate
}

// out[r, e] = sum_j values[r, j] * MT[j*E + e]
// 128 blocks x 1024 threads: wave w handles row r0+w; MT loads coalesced
// across e and shared by all 4 waves (L1).
__global__ __launch_bounds__(1024) void apply_kernel(
    const float* __restrict__ values, const float* __restrict__ MT,
    float* __restrict__ out)
{
    const int tid = threadIdx.x;
    const int e   = tid & 255;
    const int w   = tid >> 8;
    const int r0  = blockIdx.x * 4;

    __shared__ float sv[4][256];
    sv[w][e] = values[(r0 + w) * E + e];
    __syncthreads();

    float acc0 = 0.f, acc1 = 0.f;       // 2 chains for FMA-latency ILP
    #pragma unroll 8
    for (int j = 0; j < E; j += 2) {
        acc0 += sv[w][j]     * MT[(j)     * E + e];
        acc1 += sv[w][j + 1] * MT[(j + 1) * E + e];
    }
    out[(r0 + w) * E + e] = acc0 + acc1;
}

extern "C" void kernel_launch(void* const* d_in, const int* in_sizes, int n_in,
                              void* d_out, int out_size, void* d_ws, size_t ws_size,
                              hipStream_t stream) {
    // inputs: 0 pos_emb(unused) 1 values 2 ln_w 3 ln_b 4 Wq 5 Wk 6 Wv 7 Wp
    const float* values = (const float*)d_in[1];
    const float* Wv     = (const float*)d_in[6];
    const float* Wp     = (const float*)d_in[7];
    float*       out    = (float*)d_out;
    float*       MT     = (float*)d_ws;   // E*E floats = 256 KB scratch

    hipMemsetAsync(MT, 0, E * E * sizeof(float), stream);  // d_ws is re-poisoned each call
    build_m_kernel<<<dim3(64, 4), 1024, 0, stream>>>(Wv, Wp, MT);
    apply_kernel<<<BT / 4, 1024, 0, stream>>>(values, MT, out);
}

// Round 3
// 86.868 us; speedup vs baseline: 1.3621x; 1.1784x over previous
//
#include <hip/hip_runtime.h>

// RelativePositionAttention collapses algebraically:
//   softmax over w of (Q[t] - K[w]) is independent of Q (shift invariance),
//   and einsum('btdh,btwdh->btdh', Vh, A) = Vh * sum_w A = Vh.
// So: result = values @ M^T, with
//   M[i][j] = sum_{h,d} Wp[i*EH + d*H + h] * Wv[(h*E + d)*E + j]   (256x256)
// LayerNorm / Wq / Wk / position_embeddings are dead code.
//
// R3: R2 was still ~25-30 us per kernel (under a ~45 us harness d_ws-poison
// floor visible as 268MB fillBufferAligned dispatches). Fixes:
//  - build: float4 Wv loads, in-block k-sub-split + LDS reduce, atomics
//    coalesced into 16B groups via LDS transpose.
//  - apply: full-chip 256 blocks x 1024 thr, float4 MT loads, LDS j-reduce.

constexpr int E  = 256;
constexpr int H  = 4;
constexpr int EH = E * H;   // 1024
constexpr int BT = 512;     // B*T

// grid(64,4) x 1024 thr. bx -> rows i0..i0+3, by -> d-range [by*64, +64).
// thread: jq=tid&63 -> cols j0=jq*4..+3 (float4), w=(tid>>6)&3 -> row,
// skc=tid>>8 -> d-subrange of 16. LDS-reduce over skc, then coalesced atomic.
__global__ __launch_bounds__(1024) void build_m_kernel(
    const float* __restrict__ Wv, const float* __restrict__ Wp,
    float* __restrict__ MT)
{
    const int tid = threadIdx.x;
    const int jq  = tid & 63;
    const int j0  = jq * 4;
    const int w   = (tid >> 6) & 3;
    const int skc = tid >> 8;           // 0..3
    const int i0  = blockIdx.x * 4;
    const int dB  = blockIdx.y * 64;    // block's d-base

    // Wp rows i0..i0+3, cols [by*256, +256)  (col = d*4+h is contiguous in d,h)
    __shared__ float sWp[4][256];
    sWp[tid >> 8][tid & 255] = Wp[(i0 + (tid >> 8)) * EH + blockIdx.y * 256 + (tid & 255)];
    __syncthreads();

    float4 acc = make_float4(0.f, 0.f, 0.f, 0.f);
    #pragma unroll
    for (int h = 0; h < H; ++h) {
        const float* __restrict__ p = Wv + (h * E + dB + skc * 16) * E + j0;
        #pragma unroll
        for (int dd = 0; dd < 16; ++dd) {
            const float4 wv = *(const float4*)(p + dd * E);       // 16B coalesced
            const float  wp = sWp[w][(skc * 16 + dd) * 4 + h];    // LDS broadcast
            acc.x += wp * wv.x; acc.y += wp * wv.y;
            acc.z += wp * wv.z; acc.w += wp * wv.w;
        }
    }

    // reduce over skc in LDS, then atomicAdd in coalesced 16B groups
    __shared__ float sAcc[4][4][256];   // [skc][w][j]
    *(float4*)&sAcc[skc][w][j0] = acc;
    __syncthreads();

    const int j2 = tid >> 2;            // 0..255
    const int ii = tid & 3;             // row offset
    float v = sAcc[0][ii][j2] + sAcc[1][ii][j2] + sAcc[2][ii][j2] + sAcc[3][ii][j2];
    atomicAdd(&MT[j2 * E + i0 + ii], v);   // wave = 16 segments of 16B
}

// out[r,e] = sum_j values[r,j] * MT[j*E + e]
// grid 256 x 1024 thr (full chip). bx -> 2 rows; thread: eq=tid&63 ->
// e0=eq*4 (float4), rr=(tid>>6)&1 -> row, jc=tid>>7 -> j-range of 32.
__global__ __launch_bounds__(1024) void apply_kernel(
    const float* __restrict__ values, const float* __restrict__ MT,
    float* __restrict__ out)
{
    const int tid = threadIdx.x;
    const int eq  = tid & 63;
    const int e0  = eq * 4;
    const int rr  = (tid >> 6) & 1;
    const int jc  = tid >> 7;           // 0..7
    const int r0  = blockIdx.x * 2;

    __shared__ float sv[2][256];
    if (tid < 2 * E) sv[tid >> 8][tid & 255] = values[r0 * E + tid];
    __syncthreads();

    float4 acc = make_float4(0.f, 0.f, 0.f, 0.f);
    #pragma unroll
    for (int jj = 0; jj < 32; ++jj) {
        const int    j = jc * 32 + jj;
        const float4 m = *(const float4*)&MT[j * E + e0];          // 16B coalesced
        const float  s = sv[rr][j];                                // LDS broadcast
        acc.x += s * m.x; acc.y += s * m.y; acc.z += s * m.z; acc.w += s * m.w;
    }

    __shared__ float sAcc[8][2][256];   // [jc][rr][e]
    *(float4*)&sAcc[jc][rr][e0] = acc;
    __syncthreads();

    if (tid < 2 * E) {
        const int r_idx = tid >> 8, e = tid & 255;
        float v = 0.f;
        #pragma unroll
        for (int c = 0; c < 8; ++c) v += sAcc[c][r_idx][e];        // conflict-free
        out[(r0 + r_idx) * E + e] = v;                             // coalesced
    }
}

extern "C" void kernel_launch(void* const* d_in, const int* in_sizes, int n_in,
                              void* d_out, int out_size, void* d_ws, size_t ws_size,
                              hipStream_t stream) {
    // inputs: 0 pos_emb(unused) 1 values 2 ln_w 3 ln_b 4 Wq 5 Wk 6 Wv 7 Wp
    const float* values = (const float*)d_in[1];
    const float* Wv     = (const float*)d_in[6];
    const float* Wp     = (const float*)d_in[7];
    float*       out    = (float*)d_out;
    float*       MT     = (float*)d_ws;   // E*E floats = 256 KB scratch

    hipMemsetAsync(MT, 0, E * E * sizeof(float), stream);  // d_ws is poisoned each call
    build_m_kernel<<<dim3(64, 4), 1024, 0, stream>>>(Wv, Wp, MT);
    apply_kernel<<<BT / 2, 1024, 0, stream>>>(values, MT, out);
}